// Round 12
// baseline (314.459 us; speedup 1.0000x reference)
//
#include <hip/hip_runtime.h>

#define N_NODES 20000
#define N_EDGES 320000
#define C 64
#define NATTR 10
#define MSG_DIM 576      // C*(1+3+5)
#define WC_COLS 192      // 3*C
#define PRE 12           // per-wave snd/xs prefetch depth

// ---------------------------------------------------------------------------
// Kernel 1: h = node_feats @ (W_lin1 / 8).  Also zeroes counts[].
// ---------------------------------------------------------------------------
__global__ void node_linear(const float* __restrict__ nf,
                            const float* __restrict__ W,
                            float* __restrict__ h,
                            int* __restrict__ counts) {
    const int t = threadIdx.x;
    if (blockIdx.x < 79) {
        const int i = blockIdx.x * 256 + t;
        if (i < N_NODES) counts[i] = 0;
    }
    __shared__ float Ws[64 * 64];
    __shared__ float row[4][64];
    const int lane = t & 63, wv = t >> 6;
    for (int i = t; i < 4096; i += 256) Ws[i] = W[i] * 0.125f;
    __syncthreads();
    const int base = blockIdx.x * 16;
    for (int it = 0; it < 4; ++it) {
        int n = base + it * 4 + wv;
        if (n >= N_NODES) break;
        row[wv][lane] = nf[(size_t)n * 64 + lane];
        float acc = 0.f;
        #pragma unroll
        for (int k = 0; k < 64; ++k) acc += row[wv][k] * Ws[k * 64 + lane];
        h[(size_t)n * 64 + lane] = acc;
    }
}

// ---------------------------------------------------------------------------
// Kernel 2: histogram of receivers.
// ---------------------------------------------------------------------------
__global__ void hist_kernel(const int* __restrict__ eidx, int* __restrict__ counts) {
    const int e = blockIdx.x * 256 + threadIdx.x;
    if (e < N_EDGES) atomicAdd(&counts[eidx[N_EDGES + e]], 1);
}

// ---------------------------------------------------------------------------
// Kernel 3 (FUSED 1-block): prefix scan + radial collapse + W_msg transpose
// (scale 1/128 folded) + pad zeroing.
// ---------------------------------------------------------------------------
#define SCAN_PER 20   // 1024 * 20 = 20480 >= 20000
__global__ __launch_bounds__(1024) void scan_radial_kernel(
        const int* __restrict__ counts,
        int* __restrict__ start, int* __restrict__ cursor,
        const float* __restrict__ Wr0, const float* __restrict__ Wr1,
        const float* __restrict__ Wr2, const float* __restrict__ Wr3,
        float* __restrict__ Wc,
        const float* __restrict__ Wmsg, float* __restrict__ WmsgT,
        int* __restrict__ snd_pad) {
    __shared__ int wsum[16];
    __shared__ float T[8 * 64];
    __shared__ float T2[8 * 64];
    const int t = threadIdx.x, lane = t & 63, w = t >> 6;
    const float s0r = 0.35355339059327373f;  // 1/sqrt(8)
    const float s1r = 0.125f;                // 1/8

    const int base = t * SCAN_PER;
    int v[SCAN_PER];
    int s = 0;
    #pragma unroll
    for (int j = 0; j < SCAN_PER; ++j) {
        const int idx = base + j;
        v[j] = (idx < N_NODES) ? counts[idx] : 0;
        s += v[j];
    }
    int sc = s;
    #pragma unroll
    for (int off = 1; off < 64; off <<= 1) {
        int up = __shfl_up(sc, off);
        if (lane >= off) sc += up;
    }
    if (lane == 63) wsum[w] = sc;
    if (t < 16) snd_pad[t] = 0;
    // W_msg transpose with folded 1/128 scale: WT[l][v][u] = W[l][u][v]/128
    for (int i = t; i < 3 * 4096; i += 1024) {
        const int l = i >> 12, r = (i >> 6) & 63, c2 = i & 63;
        WmsgT[i] = Wmsg[(l << 12) + (c2 << 6) + r] * (1.f / 128.f);
    }
    for (int i = t; i < 8 * 64; i += 1024) {
        int r = i >> 6, c2 = i & 63;
        float acc = 0.f;
        for (int k = 0; k < 64; ++k) acc += Wr0[r * 64 + k] * Wr1[k * 64 + c2];
        T[i] = acc * (s0r * s1r);
    }
    __syncthreads();
    if (t == 0) {
        int a = 0;
        #pragma unroll
        for (int i = 0; i < 16; ++i) { int x = wsum[i]; wsum[i] = a; a += x; }
    }
    for (int i = t; i < 8 * 64; i += 1024) {
        int r = i >> 6, c2 = i & 63;
        float acc = 0.f;
        for (int k = 0; k < 64; ++k) acc += T[r * 64 + k] * Wr2[k * 64 + c2];
        T2[i] = acc * s1r;
    }
    __syncthreads();
    int a = wsum[w] + (sc - s);   // exclusive prefix for this thread
    #pragma unroll
    for (int j = 0; j < SCAN_PER; ++j) {
        const int idx = base + j;
        if (idx < N_NODES) {
            start[idx] = a;
            cursor[idx] = a;
            a += v[j];
        }
    }
    for (int i = t; i < 8 * WC_COLS; i += 1024) {
        int r = i / WC_COLS, c2 = i % WC_COLS;
        float acc = 0.f;
        for (int k = 0; k < 64; ++k) acc += T2[r * 64 + k] * Wr3[k * WC_COLS + c2];
        Wc[i] = acc * s1r;
    }
}

// ---------------------------------------------------------------------------
// Kernel 4: counting-sort scatter materializing sorted records.
// ---------------------------------------------------------------------------
__global__ void scatter_build(const int* __restrict__ eidx,
                              const float* __restrict__ ef,
                              const float* __restrict__ ea,
                              int* __restrict__ cursor,
                              int* __restrict__ snd_s,
                              float* __restrict__ ef_s,
                              float* __restrict__ ea_s) {
    const int e = blockIdx.x * 256 + threadIdx.x;
    if (e >= N_EDGES) return;
    const int r = eidx[N_EDGES + e];
    const int pos = atomicAdd(&cursor[r], 1);
    snd_s[pos] = eidx[e];
    const float4* s4 = reinterpret_cast<const float4*>(ef + (size_t)e * 8);
    float4* d4 = reinterpret_cast<float4*>(ef_s + (size_t)pos * 8);
    d4[0] = s4[0];
    d4[1] = s4[1];
    const float* y = ea + (size_t)e * 9;
    float4* o4 = reinterpret_cast<float4*>(ea_s + (size_t)pos * 12);
    o4[0] = make_float4(y[0], y[1], y[2], y[3]);
    o4[1] = make_float4(y[4], y[5], y[6], y[7]);
    o4[2] = make_float4(y[8], 0.f, 0.f, 0.f);
}

// ---------------------------------------------------------------------------
// Kernel 5: FUSED gather + W_msg transform. Epilogue uses transposed W
// (per-lane contiguous float4 rows, scale folded) + LDS float4 part reads:
// 32 global float4 + 64 LDS b128 + 256 FMA per wave (was ~1200 scalar ops).
// ---------------------------------------------------------------------------
__global__ __launch_bounds__(256) void gather_fused(
                              const float* __restrict__ ef_s,  // E x 8 sorted
                              const float* __restrict__ ea_s,  // E x 12 sorted
                              const int* __restrict__ snd_s,   // E+16 sorted
                              const float* __restrict__ h,     // N x 64
                              const float* __restrict__ Wc,    // 8 x 192
                              const float* __restrict__ WmsgT, // 3*64*64 transposed, scaled
                              const int* __restrict__ start,
                              const int* __restrict__ counts,
                              float* __restrict__ out) {       // N x 576 final
    __shared__ __align__(16) float part[2][9][64];
    const int t = threadIdx.x, lane = t & 63, wv = t >> 6;
    const int g = wv >> 1;               // node slot within block (0,1)
    const int half = wv & 1;             // which half of the edge list
    const int n = blockIdx.x * 2 + g;

    float wc0[8], wc1[8], wc2[8];
    #pragma unroll
    for (int k = 0; k < 8; ++k) {
        wc0[k] = Wc[k * WC_COLS + lane];
        wc1[k] = Wc[k * WC_COLS + 64 + lane];
        wc2[k] = Wc[k * WC_COLS + 128 + lane];
    }

    float p0 = 0.f;
    float p1[3] = {0.f, 0.f, 0.f};
    float p2[5] = {0.f, 0.f, 0.f, 0.f, 0.f};

    {
        const int s0 = start[n], cnt = counts[n];
        const int jbeg = half ? (cnt >> 1) : 0;
        const int jend = half ? cnt : (cnt >> 1);
        const int m = jend - jbeg;
        const int base = s0 + jbeg;

        if (m > 0) {
            const int P = (m < PRE) ? m : PRE;
            int snd[PRE];
            #pragma unroll
            for (int b = 0; b < PRE; ++b) snd[b] = snd_s[base + b];  // pad-safe
            float xs[PRE];
            #pragma unroll
            for (int b = 0; b < PRE; ++b) {
                const int sb = (b < P) ? snd[b] : snd[0];
                xs[b] = h[(size_t)sb * 64 + lane];
            }
            #pragma unroll
            for (int jj = 0; jj < PRE / 2; ++jj) {
                const int j = jj * 2;
                if (j < P) {
                    const bool has2 = (j + 1 < P);
                    const int j1 = has2 ? (j + 1) : j;
                    const float gate1 = has2 ? 1.f : 0.f;
                    const float4* q0e = reinterpret_cast<const float4*>(ef_s + (size_t)(base + j) * 8);
                    const float4* q1e = reinterpret_cast<const float4*>(ef_s + (size_t)(base + j1) * 8);
                    const float4* q0a = reinterpret_cast<const float4*>(ea_s + (size_t)(base + j) * 12);
                    const float4* q1a = reinterpret_cast<const float4*>(ea_s + (size_t)(base + j1) * 12);
                    const float4 e00 = q0e[0], e01 = q0e[1];
                    const float4 e10 = q1e[0], e11 = q1e[1];
                    const float4 a00 = q0a[0], a01 = q0a[1], a02 = q0a[2];
                    const float4 a10 = q1a[0], a11 = q1a[1], a12 = q1a[2];
                    const float xa = xs[j];
                    const float xb = (has2 ? xs[j + 1] : 0.f) * gate1;
                    {
                        const float* fk = reinterpret_cast<const float*>(&e00);
                        const float* gk = reinterpret_cast<const float*>(&e01);
                        float w0 = fk[0] * wc0[0], w1 = fk[0] * wc1[0], w2 = fk[0] * wc2[0];
                        #pragma unroll
                        for (int k = 1; k < 4; ++k) {
                            w0 += fk[k] * wc0[k]; w1 += fk[k] * wc1[k]; w2 += fk[k] * wc2[k];
                        }
                        #pragma unroll
                        for (int k = 0; k < 4; ++k) {
                            w0 += gk[k] * wc0[k + 4]; w1 += gk[k] * wc1[k + 4]; w2 += gk[k] * wc2[k + 4];
                        }
                        const float b0 = xa * w0, b1 = xa * w1, b2 = xa * w2;
                        p0    += b0 * a00.x;
                        p1[0] += b1 * a00.y; p1[1] += b1 * a00.z; p1[2] += b1 * a00.w;
                        p2[0] += b2 * a01.x; p2[1] += b2 * a01.y; p2[2] += b2 * a01.z;
                        p2[3] += b2 * a01.w; p2[4] += b2 * a02.x;
                    }
                    {
                        const float* fk = reinterpret_cast<const float*>(&e10);
                        const float* gk = reinterpret_cast<const float*>(&e11);
                        float w0 = fk[0] * wc0[0], w1 = fk[0] * wc1[0], w2 = fk[0] * wc2[0];
                        #pragma unroll
                        for (int k = 1; k < 4; ++k) {
                            w0 += fk[k] * wc0[k]; w1 += fk[k] * wc1[k]; w2 += fk[k] * wc2[k];
                        }
                        #pragma unroll
                        for (int k = 0; k < 4; ++k) {
                            w0 += gk[k] * wc0[k + 4]; w1 += gk[k] * wc1[k + 4]; w2 += gk[k] * wc2[k + 4];
                        }
                        const float b0 = xb * w0, b1 = xb * w1, b2 = xb * w2;
                        p0    += b0 * a10.x;
                        p1[0] += b1 * a10.y; p1[1] += b1 * a10.z; p1[2] += b1 * a10.w;
                        p2[0] += b2 * a11.x; p2[1] += b2 * a11.y; p2[2] += b2 * a11.z;
                        p2[3] += b2 * a11.w; p2[4] += b2 * a12.x;
                    }
                }
            }
            for (int j = PRE; j < m; ++j) {   // rare tail m > PRE
                const size_t r0 = (size_t)(base + j);
                const int snd_t = snd_s[r0];
                const float4* pf = reinterpret_cast<const float4*>(ef_s + r0 * 8);
                const float4 fa = pf[0], fb = pf[1];
                const float4* py = reinterpret_cast<const float4*>(ea_s + r0 * 12);
                const float4 ya = py[0], yb = py[1], yc = py[2];
                const float xs_t = h[(size_t)snd_t * 64 + lane];
                const float* fk = reinterpret_cast<const float*>(&fa);
                const float* gk = reinterpret_cast<const float*>(&fb);
                float w0 = fk[0] * wc0[0], w1 = fk[0] * wc1[0], w2 = fk[0] * wc2[0];
                #pragma unroll
                for (int k = 1; k < 4; ++k) {
                    w0 += fk[k] * wc0[k]; w1 += fk[k] * wc1[k]; w2 += fk[k] * wc2[k];
                }
                #pragma unroll
                for (int k = 0; k < 4; ++k) {
                    w0 += gk[k] * wc0[k + 4]; w1 += gk[k] * wc1[k + 4]; w2 += gk[k] * wc2[k + 4];
                }
                const float b0 = xs_t * w0, b1 = xs_t * w1, b2 = xs_t * w2;
                p0    += b0 * ya.x;
                p1[0] += b1 * ya.y; p1[1] += b1 * ya.z; p1[2] += b1 * ya.w;
                p2[0] += b2 * yb.x; p2[1] += b2 * yb.y; p2[2] += b2 * yb.z;
                p2[3] += b2 * yb.w; p2[4] += b2 * yc.x;
            }
        }
    }

    // ---- combine halves into part[g][m][u] (u = lane) ----
    if (half) {
        part[g][0][lane] = p0;
        #pragma unroll
        for (int m2 = 0; m2 < 3; ++m2) part[g][1 + m2][lane] = p1[m2];
        #pragma unroll
        for (int m2 = 0; m2 < 5; ++m2) part[g][4 + m2][lane] = p2[m2];
    }
    __syncthreads();
    if (!half) {
        part[g][0][lane] += p0;
        #pragma unroll
        for (int m2 = 0; m2 < 3; ++m2) part[g][1 + m2][lane] += p1[m2];
        #pragma unroll
        for (int m2 = 0; m2 < 5; ++m2) part[g][4 + m2][lane] += p2[m2];
    }
    __syncthreads();

    // ---- in-block W_msg transform; lane = output channel v ----
    float* op = out + (size_t)n * MSG_DIM + lane * 9;
    if (!half) {
        const float* wt0 = WmsgT + lane * 64;          // l=0 row (contiguous)
        const float* wt1 = WmsgT + 4096 + lane * 64;   // l=1 row
        float o0 = 0.f, o1 = 0.f, o2 = 0.f, o3 = 0.f;
        #pragma unroll
        for (int c = 0; c < 16; ++c) {
            const int u0 = c * 4;
            const float4 w0 = *reinterpret_cast<const float4*>(wt0 + u0);
            const float4 w1 = *reinterpret_cast<const float4*>(wt1 + u0);
            const float4 pA = *reinterpret_cast<const float4*>(&part[g][0][u0]);
            const float4 pB = *reinterpret_cast<const float4*>(&part[g][1][u0]);
            const float4 pC = *reinterpret_cast<const float4*>(&part[g][2][u0]);
            const float4 pD = *reinterpret_cast<const float4*>(&part[g][3][u0]);
            o0 += pA.x * w0.x + pA.y * w0.y + pA.z * w0.z + pA.w * w0.w;
            o1 += pB.x * w1.x + pB.y * w1.y + pB.z * w1.z + pB.w * w1.w;
            o2 += pC.x * w1.x + pC.y * w1.y + pC.z * w1.z + pC.w * w1.w;
            o3 += pD.x * w1.x + pD.y * w1.y + pD.z * w1.z + pD.w * w1.w;
        }
        op[0] = o0;
        op[1] = o1;
        op[2] = o2;
        op[3] = o3;
    } else {
        const float* wt2 = WmsgT + 8192 + lane * 64;   // l=2 row
        float o4 = 0.f, o5 = 0.f, o6 = 0.f, o7 = 0.f, o8 = 0.f;
        #pragma unroll
        for (int c = 0; c < 16; ++c) {
            const int u0 = c * 4;
            const float4 w2 = *reinterpret_cast<const float4*>(wt2 + u0);
            const float4 pA = *reinterpret_cast<const float4*>(&part[g][4][u0]);
            const float4 pB = *reinterpret_cast<const float4*>(&part[g][5][u0]);
            const float4 pC = *reinterpret_cast<const float4*>(&part[g][6][u0]);
            const float4 pD = *reinterpret_cast<const float4*>(&part[g][7][u0]);
            const float4 pE = *reinterpret_cast<const float4*>(&part[g][8][u0]);
            o4 += pA.x * w2.x + pA.y * w2.y + pA.z * w2.z + pA.w * w2.w;
            o5 += pB.x * w2.x + pB.y * w2.y + pB.z * w2.z + pB.w * w2.w;
            o6 += pC.x * w2.x + pC.y * w2.y + pC.z * w2.z + pC.w * w2.w;
            o7 += pD.x * w2.x + pD.y * w2.y + pD.z * w2.z + pD.w * w2.w;
            o8 += pE.x * w2.x + pE.y * w2.y + pE.z * w2.z + pE.w * w2.w;
        }
        op[4] = o4;
        op[5] = o5;
        op[6] = o6;
        op[7] = o7;
        op[8] = o8;
    }
}

// ---------------------------------------------------------------------------
// Kernel 6: sc[n,w] = sum_{u,v} h[n,u]*attrs[n,v]*W_skip[u,v,w] / sqrt(640)
// ---------------------------------------------------------------------------
__global__ __launch_bounds__(256) void skip_kernel(
                            const float* __restrict__ h,
                            const float* __restrict__ attrs,
                            const float* __restrict__ Wskip,  // 64*10*64
                            float* __restrict__ sc) {
    __shared__ float hl[32 * 64];
    const int t = threadIdx.x, lane = t & 63, wv = t >> 6;
    const int nb = blockIdx.x * 32;
    for (int i = t; i < 32 * 64; i += 256) hl[i] = h[(size_t)(nb + (i >> 6)) * 64 + (i & 63)];
    __syncthreads();

    float alr[8][NATTR];
    #pragma unroll
    for (int i = 0; i < 8; ++i) {
        const float* ap = attrs + (size_t)(nb + wv + 4 * i) * NATTR;
        #pragma unroll
        for (int v = 0; v < NATTR; ++v) alr[i][v] = ap[v];
    }

    float acc[8] = {0.f, 0.f, 0.f, 0.f, 0.f, 0.f, 0.f, 0.f};
    #pragma unroll 1
    for (int u4 = 0; u4 < 16; ++u4) {
        const int u0 = u4 * 4;
        float4 hu[8];
        #pragma unroll
        for (int i = 0; i < 8; ++i)
            hu[i] = *reinterpret_cast<const float4*>(&hl[(wv + 4 * i) * 64 + u0]);
        #pragma unroll
        for (int uu = 0; uu < 4; ++uu) {
            float tmp[8] = {0.f, 0.f, 0.f, 0.f, 0.f, 0.f, 0.f, 0.f};
            #pragma unroll
            for (int v = 0; v < NATTR; ++v) {
                const float wk = Wskip[((u0 + uu) * NATTR + v) * 64 + lane];
                #pragma unroll
                for (int i = 0; i < 8; ++i) tmp[i] += alr[i][v] * wk;
            }
            #pragma unroll
            for (int i = 0; i < 8; ++i) {
                const float huv = (uu == 0) ? hu[i].x : (uu == 1) ? hu[i].y
                                 : (uu == 2) ? hu[i].z : hu[i].w;
                acc[i] += huv * tmp[i];
            }
        }
    }
    const float scale = 0.03952847075210474f;  // 1/sqrt(640)
    #pragma unroll
    for (int i = 0; i < 8; ++i)
        sc[(size_t)(nb + wv + 4 * i) * 64 + lane] = acc[i] * scale;
}

// ---------------------------------------------------------------------------
extern "C" void kernel_launch(void* const* d_in, const int* in_sizes, int n_in,
                              void* d_out, int out_size, void* d_ws, size_t ws_size,
                              hipStream_t stream) {
    const float* node_attrs = (const float*)d_in[0];
    const float* node_feats = (const float*)d_in[1];
    const float* edge_attrs = (const float*)d_in[2];
    const float* edge_feats = (const float*)d_in[3];
    const int*   edge_index = (const int*)d_in[4];
    const float* W_lin1 = (const float*)d_in[5];
    const float* W_r0 = (const float*)d_in[6];
    const float* W_r1 = (const float*)d_in[7];
    const float* W_r2 = (const float*)d_in[8];
    const float* W_r3 = (const float*)d_in[9];
    const float* W_msg = (const float*)d_in[10];
    const float* W_skip = (const float*)d_in[11];

    float* out = (float*)d_out;                       // N x 576 final
    float* sc  = out + (size_t)N_NODES * MSG_DIM;     // N x 64

    float* wsf = (float*)d_ws;
    float* Wc = wsf;                          // 2048 floats
    float* h  = wsf + 2048;                   // N*64
    int* wsi   = (int*)(wsf + 2048 + (size_t)N_NODES * 64);
    int* counts = wsi;                        // N
    int* start  = wsi + N_NODES;              // N
    int* cursor = wsi + 2 * N_NODES;          // N
    int*   snd_s = wsi + 3 * N_NODES;                 // E + 16 (pad)
    float* ef_s  = (float*)(snd_s + N_EDGES + 16);    // E*8
    float* ea_s  = ef_s + (size_t)N_EDGES * 8;        // E*12
    float* WmsgT = ea_s + (size_t)N_EDGES * 12;       // 3*64*64

    node_linear<<<1250, 256, 0, stream>>>(node_feats, W_lin1, h, counts);
    hist_kernel<<<(N_EDGES + 255) / 256, 256, 0, stream>>>(edge_index, counts);
    scan_radial_kernel<<<1, 1024, 0, stream>>>(counts, start, cursor,
                                               W_r0, W_r1, W_r2, W_r3, Wc,
                                               W_msg, WmsgT, snd_s + N_EDGES);
    scatter_build<<<(N_EDGES + 255) / 256, 256, 0, stream>>>(
        edge_index, edge_feats, edge_attrs, cursor, snd_s, ef_s, ea_s);

    gather_fused<<<N_NODES / 2, 256, 0, stream>>>(
        ef_s, ea_s, snd_s, h, Wc, WmsgT, start, counts, out);

    skip_kernel<<<625, 256, 0, stream>>>(h, node_attrs, W_skip, sc);
}

// Round 13
// 246.613 us; speedup vs baseline: 1.2751x; 1.2751x over previous
//
#include <hip/hip_runtime.h>

#define N_NODES 20000
#define N_EDGES 320000
#define C 64
#define NATTR 10
#define MSG_DIM 576      // C*(1+3+5)
#define WC_COLS 192      // 3*C
#define PRE 12           // per-wave snd/xs prefetch depth

// ---------------------------------------------------------------------------
// Kernel 1: h = node_feats @ (W_lin1 / 8).  Also zeroes counts[].
// ---------------------------------------------------------------------------
__global__ void node_linear(const float* __restrict__ nf,
                            const float* __restrict__ W,
                            float* __restrict__ h,
                            int* __restrict__ counts) {
    const int t = threadIdx.x;
    if (blockIdx.x < 79) {
        const int i = blockIdx.x * 256 + t;
        if (i < N_NODES) counts[i] = 0;
    }
    __shared__ float Ws[64 * 64];
    __shared__ float row[4][64];
    const int lane = t & 63, wv = t >> 6;
    for (int i = t; i < 4096; i += 256) Ws[i] = W[i] * 0.125f;
    __syncthreads();
    const int base = blockIdx.x * 16;
    for (int it = 0; it < 4; ++it) {
        int n = base + it * 4 + wv;
        if (n >= N_NODES) break;
        row[wv][lane] = nf[(size_t)n * 64 + lane];
        float acc = 0.f;
        #pragma unroll
        for (int k = 0; k < 64; ++k) acc += row[wv][k] * Ws[k * 64 + lane];
        h[(size_t)n * 64 + lane] = acc;
    }
}

// ---------------------------------------------------------------------------
// Kernel 2: histogram of receivers.
// ---------------------------------------------------------------------------
__global__ void hist_kernel(const int* __restrict__ eidx, int* __restrict__ counts) {
    const int e = blockIdx.x * 256 + threadIdx.x;
    if (e < N_EDGES) atomicAdd(&counts[eidx[N_EDGES + e]], 1);
}

// ---------------------------------------------------------------------------
// Kernel 3 (FUSED 1-block): prefix scan + radial collapse + pad zeroing.
// ---------------------------------------------------------------------------
#define SCAN_PER 20   // 1024 * 20 = 20480 >= 20000
__global__ __launch_bounds__(1024) void scan_radial_kernel(
        const int* __restrict__ counts,
        int* __restrict__ start, int* __restrict__ cursor,
        const float* __restrict__ Wr0, const float* __restrict__ Wr1,
        const float* __restrict__ Wr2, const float* __restrict__ Wr3,
        float* __restrict__ Wc, int* __restrict__ snd_pad) {
    __shared__ int wsum[16];
    __shared__ float T[8 * 64];
    __shared__ float T2[8 * 64];
    const int t = threadIdx.x, lane = t & 63, w = t >> 6;
    const float s0r = 0.35355339059327373f;  // 1/sqrt(8)
    const float s1r = 0.125f;                // 1/8

    const int base = t * SCAN_PER;
    int v[SCAN_PER];
    int s = 0;
    #pragma unroll
    for (int j = 0; j < SCAN_PER; ++j) {
        const int idx = base + j;
        v[j] = (idx < N_NODES) ? counts[idx] : 0;
        s += v[j];
    }
    int sc = s;
    #pragma unroll
    for (int off = 1; off < 64; off <<= 1) {
        int up = __shfl_up(sc, off);
        if (lane >= off) sc += up;
    }
    if (lane == 63) wsum[w] = sc;
    if (t < 16) snd_pad[t] = 0;
    for (int i = t; i < 8 * 64; i += 1024) {
        int r = i >> 6, c2 = i & 63;
        float acc = 0.f;
        for (int k = 0; k < 64; ++k) acc += Wr0[r * 64 + k] * Wr1[k * 64 + c2];
        T[i] = acc * (s0r * s1r);
    }
    __syncthreads();
    if (t == 0) {
        int a = 0;
        #pragma unroll
        for (int i = 0; i < 16; ++i) { int x = wsum[i]; wsum[i] = a; a += x; }
    }
    for (int i = t; i < 8 * 64; i += 1024) {
        int r = i >> 6, c2 = i & 63;
        float acc = 0.f;
        for (int k = 0; k < 64; ++k) acc += T[r * 64 + k] * Wr2[k * 64 + c2];
        T2[i] = acc * s1r;
    }
    __syncthreads();
    int a = wsum[w] + (sc - s);   // exclusive prefix for this thread
    #pragma unroll
    for (int j = 0; j < SCAN_PER; ++j) {
        const int idx = base + j;
        if (idx < N_NODES) {
            start[idx] = a;
            cursor[idx] = a;
            a += v[j];
        }
    }
    for (int i = t; i < 8 * WC_COLS; i += 1024) {
        int r = i / WC_COLS, c2 = i % WC_COLS;
        float acc = 0.f;
        for (int k = 0; k < 64; ++k) acc += T2[r * 64 + k] * Wr3[k * WC_COLS + c2];
        Wc[i] = acc * s1r;
    }
}

// ---------------------------------------------------------------------------
// Kernel 4: counting-sort scatter materializing sorted records.
// ---------------------------------------------------------------------------
__global__ void scatter_build(const int* __restrict__ eidx,
                              const float* __restrict__ ef,
                              const float* __restrict__ ea,
                              int* __restrict__ cursor,
                              int* __restrict__ snd_s,
                              float* __restrict__ ef_s,
                              float* __restrict__ ea_s) {
    const int e = blockIdx.x * 256 + threadIdx.x;
    if (e >= N_EDGES) return;
    const int r = eidx[N_EDGES + e];
    const int pos = atomicAdd(&cursor[r], 1);
    snd_s[pos] = eidx[e];
    const float4* s4 = reinterpret_cast<const float4*>(ef + (size_t)e * 8);
    float4* d4 = reinterpret_cast<float4*>(ef_s + (size_t)pos * 8);
    d4[0] = s4[0];
    d4[1] = s4[1];
    const float* y = ea + (size_t)e * 9;
    float4* o4 = reinterpret_cast<float4*>(ea_s + (size_t)pos * 12);
    o4[0] = make_float4(y[0], y[1], y[2], y[3]);
    o4[1] = make_float4(y[4], y[5], y[6], y[7]);
    o4[2] = make_float4(y[8], 0.f, 0.f, 0.f);
}

// ---------------------------------------------------------------------------
// Kernel 5: FUSED gather + W_msg transform. Epilogue: COALESCED scalar W
// loads (lane = v, original W layout — r11) + float4 LDS part reads (r12's
// one good piece). 128 coalesced loads + 64 LDS b128 + 256 FMA per wave.
// ---------------------------------------------------------------------------
__global__ __launch_bounds__(256) void gather_fused(
                              const float* __restrict__ ef_s,  // E x 8 sorted
                              const float* __restrict__ ea_s,  // E x 12 sorted
                              const int* __restrict__ snd_s,   // E+16 sorted
                              const float* __restrict__ h,     // N x 64
                              const float* __restrict__ Wc,    // 8 x 192
                              const float* __restrict__ Wmsg,  // 3*64*64 original
                              const int* __restrict__ start,
                              const int* __restrict__ counts,
                              float* __restrict__ out) {       // N x 576 final
    __shared__ __align__(16) float part[2][9][64];
    const int t = threadIdx.x, lane = t & 63, wv = t >> 6;
    const int g = wv >> 1;               // node slot within block (0,1)
    const int half = wv & 1;             // which half of the edge list
    const int n = blockIdx.x * 2 + g;

    float wc0[8], wc1[8], wc2[8];
    #pragma unroll
    for (int k = 0; k < 8; ++k) {
        wc0[k] = Wc[k * WC_COLS + lane];
        wc1[k] = Wc[k * WC_COLS + 64 + lane];
        wc2[k] = Wc[k * WC_COLS + 128 + lane];
    }

    float p0 = 0.f;
    float p1[3] = {0.f, 0.f, 0.f};
    float p2[5] = {0.f, 0.f, 0.f, 0.f, 0.f};

    {
        const int s0 = start[n], cnt = counts[n];
        const int jbeg = half ? (cnt >> 1) : 0;
        const int jend = half ? cnt : (cnt >> 1);
        const int m = jend - jbeg;
        const int base = s0 + jbeg;

        if (m > 0) {
            const int P = (m < PRE) ? m : PRE;
            int snd[PRE];
            #pragma unroll
            for (int b = 0; b < PRE; ++b) snd[b] = snd_s[base + b];  // pad-safe
            float xs[PRE];
            #pragma unroll
            for (int b = 0; b < PRE; ++b) {
                const int sb = (b < P) ? snd[b] : snd[0];
                xs[b] = h[(size_t)sb * 64 + lane];
            }
            #pragma unroll
            for (int jj = 0; jj < PRE / 2; ++jj) {
                const int j = jj * 2;
                if (j < P) {
                    const bool has2 = (j + 1 < P);
                    const int j1 = has2 ? (j + 1) : j;
                    const float gate1 = has2 ? 1.f : 0.f;
                    const float4* q0e = reinterpret_cast<const float4*>(ef_s + (size_t)(base + j) * 8);
                    const float4* q1e = reinterpret_cast<const float4*>(ef_s + (size_t)(base + j1) * 8);
                    const float4* q0a = reinterpret_cast<const float4*>(ea_s + (size_t)(base + j) * 12);
                    const float4* q1a = reinterpret_cast<const float4*>(ea_s + (size_t)(base + j1) * 12);
                    const float4 e00 = q0e[0], e01 = q0e[1];
                    const float4 e10 = q1e[0], e11 = q1e[1];
                    const float4 a00 = q0a[0], a01 = q0a[1], a02 = q0a[2];
                    const float4 a10 = q1a[0], a11 = q1a[1], a12 = q1a[2];
                    const float xa = xs[j];
                    const float xb = (has2 ? xs[j + 1] : 0.f) * gate1;
                    {
                        const float* fk = reinterpret_cast<const float*>(&e00);
                        const float* gk = reinterpret_cast<const float*>(&e01);
                        float w0 = fk[0] * wc0[0], w1 = fk[0] * wc1[0], w2 = fk[0] * wc2[0];
                        #pragma unroll
                        for (int k = 1; k < 4; ++k) {
                            w0 += fk[k] * wc0[k]; w1 += fk[k] * wc1[k]; w2 += fk[k] * wc2[k];
                        }
                        #pragma unroll
                        for (int k = 0; k < 4; ++k) {
                            w0 += gk[k] * wc0[k + 4]; w1 += gk[k] * wc1[k + 4]; w2 += gk[k] * wc2[k + 4];
                        }
                        const float b0 = xa * w0, b1 = xa * w1, b2 = xa * w2;
                        p0    += b0 * a00.x;
                        p1[0] += b1 * a00.y; p1[1] += b1 * a00.z; p1[2] += b1 * a00.w;
                        p2[0] += b2 * a01.x; p2[1] += b2 * a01.y; p2[2] += b2 * a01.z;
                        p2[3] += b2 * a01.w; p2[4] += b2 * a02.x;
                    }
                    {
                        const float* fk = reinterpret_cast<const float*>(&e10);
                        const float* gk = reinterpret_cast<const float*>(&e11);
                        float w0 = fk[0] * wc0[0], w1 = fk[0] * wc1[0], w2 = fk[0] * wc2[0];
                        #pragma unroll
                        for (int k = 1; k < 4; ++k) {
                            w0 += fk[k] * wc0[k]; w1 += fk[k] * wc1[k]; w2 += fk[k] * wc2[k];
                        }
                        #pragma unroll
                        for (int k = 0; k < 4; ++k) {
                            w0 += gk[k] * wc0[k + 4]; w1 += gk[k] * wc1[k + 4]; w2 += gk[k] * wc2[k + 4];
                        }
                        const float b0 = xb * w0, b1 = xb * w1, b2 = xb * w2;
                        p0    += b0 * a10.x;
                        p1[0] += b1 * a10.y; p1[1] += b1 * a10.z; p1[2] += b1 * a10.w;
                        p2[0] += b2 * a11.x; p2[1] += b2 * a11.y; p2[2] += b2 * a11.z;
                        p2[3] += b2 * a11.w; p2[4] += b2 * a12.x;
                    }
                }
            }
            for (int j = PRE; j < m; ++j) {   // rare tail m > PRE
                const size_t r0 = (size_t)(base + j);
                const int snd_t = snd_s[r0];
                const float4* pf = reinterpret_cast<const float4*>(ef_s + r0 * 8);
                const float4 fa = pf[0], fb = pf[1];
                const float4* py = reinterpret_cast<const float4*>(ea_s + r0 * 12);
                const float4 ya = py[0], yb = py[1], yc = py[2];
                const float xs_t = h[(size_t)snd_t * 64 + lane];
                const float* fk = reinterpret_cast<const float*>(&fa);
                const float* gk = reinterpret_cast<const float*>(&fb);
                float w0 = fk[0] * wc0[0], w1 = fk[0] * wc1[0], w2 = fk[0] * wc2[0];
                #pragma unroll
                for (int k = 1; k < 4; ++k) {
                    w0 += fk[k] * wc0[k]; w1 += fk[k] * wc1[k]; w2 += fk[k] * wc2[k];
                }
                #pragma unroll
                for (int k = 0; k < 4; ++k) {
                    w0 += gk[k] * wc0[k + 4]; w1 += gk[k] * wc1[k + 4]; w2 += gk[k] * wc2[k + 4];
                }
                const float b0 = xs_t * w0, b1 = xs_t * w1, b2 = xs_t * w2;
                p0    += b0 * ya.x;
                p1[0] += b1 * ya.y; p1[1] += b1 * ya.z; p1[2] += b1 * ya.w;
                p2[0] += b2 * yb.x; p2[1] += b2 * yb.y; p2[2] += b2 * yb.z;
                p2[3] += b2 * yb.w; p2[4] += b2 * yc.x;
            }
        }
    }

    // ---- combine halves into part[g][m][u] (u = lane) ----
    if (half) {
        part[g][0][lane] = p0;
        #pragma unroll
        for (int m2 = 0; m2 < 3; ++m2) part[g][1 + m2][lane] = p1[m2];
        #pragma unroll
        for (int m2 = 0; m2 < 5; ++m2) part[g][4 + m2][lane] = p2[m2];
    }
    __syncthreads();
    if (!half) {
        part[g][0][lane] += p0;
        #pragma unroll
        for (int m2 = 0; m2 < 3; ++m2) part[g][1 + m2][lane] += p1[m2];
        #pragma unroll
        for (int m2 = 0; m2 < 5; ++m2) part[g][4 + m2][lane] += p2[m2];
    }
    __syncthreads();

    // ---- in-block W_msg transform; lane = v (coalesced W reads) ----
    const float scale = 1.f / 128.f;  // 1/(sqrt(64)*16)
    float* op = out + (size_t)n * MSG_DIM + lane * 9;
    if (!half) {
        float o0 = 0.f, o1 = 0.f, o2 = 0.f, o3 = 0.f;
        #pragma unroll
        for (int c = 0; c < 16; ++c) {
            const int u0 = c * 4;
            const float4 pA = *reinterpret_cast<const float4*>(&part[g][0][u0]);
            const float4 pB = *reinterpret_cast<const float4*>(&part[g][1][u0]);
            const float4 pC = *reinterpret_cast<const float4*>(&part[g][2][u0]);
            const float4 pD = *reinterpret_cast<const float4*>(&part[g][3][u0]);
            const float w00 = Wmsg[(u0 + 0) * 64 + lane];
            const float w01 = Wmsg[(u0 + 1) * 64 + lane];
            const float w02 = Wmsg[(u0 + 2) * 64 + lane];
            const float w03 = Wmsg[(u0 + 3) * 64 + lane];
            const float w10 = Wmsg[4096 + (u0 + 0) * 64 + lane];
            const float w11 = Wmsg[4096 + (u0 + 1) * 64 + lane];
            const float w12 = Wmsg[4096 + (u0 + 2) * 64 + lane];
            const float w13 = Wmsg[4096 + (u0 + 3) * 64 + lane];
            o0 += pA.x * w00 + pA.y * w01 + pA.z * w02 + pA.w * w03;
            o1 += pB.x * w10 + pB.y * w11 + pB.z * w12 + pB.w * w13;
            o2 += pC.x * w10 + pC.y * w11 + pC.z * w12 + pC.w * w13;
            o3 += pD.x * w10 + pD.y * w11 + pD.z * w12 + pD.w * w13;
        }
        op[0] = o0 * scale;
        op[1] = o1 * scale;
        op[2] = o2 * scale;
        op[3] = o3 * scale;
    } else {
        float o4 = 0.f, o5 = 0.f, o6 = 0.f, o7 = 0.f, o8 = 0.f;
        #pragma unroll
        for (int c = 0; c < 16; ++c) {
            const int u0 = c * 4;
            const float4 pA = *reinterpret_cast<const float4*>(&part[g][4][u0]);
            const float4 pB = *reinterpret_cast<const float4*>(&part[g][5][u0]);
            const float4 pC = *reinterpret_cast<const float4*>(&part[g][6][u0]);
            const float4 pD = *reinterpret_cast<const float4*>(&part[g][7][u0]);
            const float4 pE = *reinterpret_cast<const float4*>(&part[g][8][u0]);
            const float w20 = Wmsg[8192 + (u0 + 0) * 64 + lane];
            const float w21 = Wmsg[8192 + (u0 + 1) * 64 + lane];
            const float w22 = Wmsg[8192 + (u0 + 2) * 64 + lane];
            const float w23 = Wmsg[8192 + (u0 + 3) * 64 + lane];
            o4 += pA.x * w20 + pA.y * w21 + pA.z * w22 + pA.w * w23;
            o5 += pB.x * w20 + pB.y * w21 + pB.z * w22 + pB.w * w23;
            o6 += pC.x * w20 + pC.y * w21 + pC.z * w22 + pC.w * w23;
            o7 += pD.x * w20 + pD.y * w21 + pD.z * w22 + pD.w * w23;
            o8 += pE.x * w20 + pE.y * w21 + pE.z * w22 + pE.w * w23;
        }
        op[4] = o4 * scale;
        op[5] = o5 * scale;
        op[6] = o6 * scale;
        op[7] = o7 * scale;
        op[8] = o8 * scale;
    }
}

// ---------------------------------------------------------------------------
// Kernel 6: sc[n,w] = sum_{u,v} h[n,u]*attrs[n,v]*W_skip[u,v,w] / sqrt(640)
// ---------------------------------------------------------------------------
__global__ __launch_bounds__(256) void skip_kernel(
                            const float* __restrict__ h,
                            const float* __restrict__ attrs,
                            const float* __restrict__ Wskip,  // 64*10*64
                            float* __restrict__ sc) {
    __shared__ float hl[32 * 64];
    const int t = threadIdx.x, lane = t & 63, wv = t >> 6;
    const int nb = blockIdx.x * 32;
    for (int i = t; i < 32 * 64; i += 256) hl[i] = h[(size_t)(nb + (i >> 6)) * 64 + (i & 63)];
    __syncthreads();

    float alr[8][NATTR];
    #pragma unroll
    for (int i = 0; i < 8; ++i) {
        const float* ap = attrs + (size_t)(nb + wv + 4 * i) * NATTR;
        #pragma unroll
        for (int v = 0; v < NATTR; ++v) alr[i][v] = ap[v];
    }

    float acc[8] = {0.f, 0.f, 0.f, 0.f, 0.f, 0.f, 0.f, 0.f};
    #pragma unroll 1
    for (int u4 = 0; u4 < 16; ++u4) {
        const int u0 = u4 * 4;
        float4 hu[8];
        #pragma unroll
        for (int i = 0; i < 8; ++i)
            hu[i] = *reinterpret_cast<const float4*>(&hl[(wv + 4 * i) * 64 + u0]);
        #pragma unroll
        for (int uu = 0; uu < 4; ++uu) {
            float tmp[8] = {0.f, 0.f, 0.f, 0.f, 0.f, 0.f, 0.f, 0.f};
            #pragma unroll
            for (int v = 0; v < NATTR; ++v) {
                const float wk = Wskip[((u0 + uu) * NATTR + v) * 64 + lane];
                #pragma unroll
                for (int i = 0; i < 8; ++i) tmp[i] += alr[i][v] * wk;
            }
            #pragma unroll
            for (int i = 0; i < 8; ++i) {
                const float huv = (uu == 0) ? hu[i].x : (uu == 1) ? hu[i].y
                                 : (uu == 2) ? hu[i].z : hu[i].w;
                acc[i] += huv * tmp[i];
            }
        }
    }
    const float scale = 0.03952847075210474f;  // 1/sqrt(640)
    #pragma unroll
    for (int i = 0; i < 8; ++i)
        sc[(size_t)(nb + wv + 4 * i) * 64 + lane] = acc[i] * scale;
}

// ---------------------------------------------------------------------------
extern "C" void kernel_launch(void* const* d_in, const int* in_sizes, int n_in,
                              void* d_out, int out_size, void* d_ws, size_t ws_size,
                              hipStream_t stream) {
    const float* node_attrs = (const float*)d_in[0];
    const float* node_feats = (const float*)d_in[1];
    const float* edge_attrs = (const float*)d_in[2];
    const float* edge_feats = (const float*)d_in[3];
    const int*   edge_index = (const int*)d_in[4];
    const float* W_lin1 = (const float*)d_in[5];
    const float* W_r0 = (const float*)d_in[6];
    const float* W_r1 = (const float*)d_in[7];
    const float* W_r2 = (const float*)d_in[8];
    const float* W_r3 = (const float*)d_in[9];
    const float* W_msg = (const float*)d_in[10];
    const float* W_skip = (const float*)d_in[11];

    float* out = (float*)d_out;                       // N x 576 final
    float* sc  = out + (size_t)N_NODES * MSG_DIM;     // N x 64

    float* wsf = (float*)d_ws;
    float* Wc = wsf;                          // 2048 floats
    float* h  = wsf + 2048;                   // N*64
    int* wsi   = (int*)(wsf + 2048 + (size_t)N_NODES * 64);
    int* counts = wsi;                        // N
    int* start  = wsi + N_NODES;              // N
    int* cursor = wsi + 2 * N_NODES;          // N
    int*   snd_s = wsi + 3 * N_NODES;                 // E + 16 (pad)
    float* ef_s  = (float*)(snd_s + N_EDGES + 16);    // E*8
    float* ea_s  = ef_s + (size_t)N_EDGES * 8;        // E*12

    node_linear<<<1250, 256, 0, stream>>>(node_feats, W_lin1, h, counts);
    hist_kernel<<<(N_EDGES + 255) / 256, 256, 0, stream>>>(edge_index, counts);
    scan_radial_kernel<<<1, 1024, 0, stream>>>(counts, start, cursor,
                                               W_r0, W_r1, W_r2, W_r3, Wc,
                                               snd_s + N_EDGES);
    scatter_build<<<(N_EDGES + 255) / 256, 256, 0, stream>>>(
        edge_index, edge_feats, edge_attrs, cursor, snd_s, ef_s, ea_s);

    gather_fused<<<N_NODES / 2, 256, 0, stream>>>(
        ef_s, ea_s, snd_s, h, Wc, W_msg, start, counts, out);

    skip_kernel<<<625, 256, 0, stream>>>(h, node_attrs, W_skip, sc);
}